// Round 14
// baseline (118.773 us; speedup 1.0000x reference)
//
#include <hip/hip_runtime.h>
#include <hip/hip_bf16.h>

// Single-head causal attention, B=4096, T=64, C=128, H=64.
// R14: grid 4096 (1 batch/block), 256 thr. Wave w owns h-tiles 3w..3w+2
// (W in 48 persistent VGPRs, R8/R10-validated incl. flipped-operand v-tiles);
// QKV B-fragments read DIRECTLY from global (coalesced: one frag-load's 64
// lanes cover 16 full 128B lines; 4 waves re-read same 32KB x[b] -> L1).
// No x staging => LDS 24KB (Q reused by P; chunk w is wave-private) and
// peak regs ~158 => waves_per_eu(3,3) fits WITHOUT spill (R12's spill was
// the +32 xr-prefetch regs) => 3 blocks/CU = 12 waves/CU, +50% TLP vs the
// 44us plateau's 8. One lds_barrier per block.

typedef __bf16 bf16_t;
typedef __bf16 bf16x8 __attribute__((ext_vector_type(8)));
typedef __bf16 bf16x4 __attribute__((ext_vector_type(4)));
typedef float  f32x4  __attribute__((ext_vector_type(4)));

#define Q_OFF   0        // Q [t][h] 64x64 bf16, swizzled, 8 KB; chunk w reused as P
#define K_OFF   8192     // K [s][h] 8 KB
#define VT_OFF  16384    // VT [h][t] 8 KB
#define LDS_BYTES 24576  // 24 KB -> LDS allows 6 blocks/CU; waves_per_eu caps at 3

__device__ __forceinline__ int swz(int off, int row) { return off ^ ((row & 7) << 4); }

// Publishes LDS writes without draining vmcnt (validated R11).
__device__ __forceinline__ void lds_barrier() {
    asm volatile("s_waitcnt lgkmcnt(0)" ::: "memory");
    __builtin_amdgcn_s_barrier();
    asm volatile("" ::: "memory");
}

__device__ __forceinline__ bf16x8 pack8(float4 a, float4 b) {
    bf16x8 r;
    r[0] = (bf16_t)a.x; r[1] = (bf16_t)a.y; r[2] = (bf16_t)a.z; r[3] = (bf16_t)a.w;
    r[4] = (bf16_t)b.x; r[5] = (bf16_t)b.y; r[6] = (bf16_t)b.z; r[7] = (bf16_t)b.w;
    return r;
}

__global__ __launch_bounds__(256) __attribute__((amdgpu_waves_per_eu(3, 3)))
void head_attn_kernel(const float* __restrict__ x,
                      const float* __restrict__ Wq,
                      const float* __restrict__ Wk,
                      const float* __restrict__ Wv,
                      float* __restrict__ out)
{
    __shared__ __align__(16) char smem[LDS_BYTES];
    const int b    = blockIdx.x;
    const int tid  = threadIdx.x;
    const int w    = tid >> 6;
    const int lane = tid & 63;
    const int l15  = lane & 15;
    const int lg   = lane >> 4;
    const int t    = w * 16 + l15;      // lane's query/time row (attention)
    const int tile0 = 3 * w;            // this wave's first h-tile
    char* pscr = smem + Q_OFF + w * 2048;   // P scratch = Q chunk w (wave-private)

    const float* xq = x + (size_t)b * 8192;

    // ---- W fragments for this wave's 3 h-tiles: persistent registers ------
    bf16x8 wfr[3][4];
    #pragma unroll
    for (int j = 0; j < 3; ++j) {
        int hg = (tile0 + j) * 16 + l15;
        const float* wr = (hg < 64)  ? Wq + hg * 128
                        : (hg < 128) ? Wk + (hg - 64) * 128
                                     : Wv + (hg - 128) * 128;
        #pragma unroll
        for (int ks = 0; ks < 4; ++ks) {
            float4 a = *(const float4*)(wr + ks * 32 + lg * 8);
            float4 c = *(const float4*)(wr + ks * 32 + lg * 8 + 4);
            wfr[j][ks] = pack8(a, c);
        }
    }

    // ------------- QKV: wave's 3 h-tiles x all 4 t-tiles -------------------
    // tile<8 (q/k): mfma(wfr, xf) -> lane = t, regs = h   [R8-validated]
    // tile>=8 (v):  mfma(xf, wfr) -> lane = h, regs = t   [R8-validated]
    f32x4 acc[3][4];
    #pragma unroll
    for (int j = 0; j < 3; ++j)
        #pragma unroll
        for (int tt = 0; tt < 4; ++tt) acc[j][tt] = (f32x4){0.f, 0.f, 0.f, 0.f};

    #pragma unroll
    for (int ks = 0; ks < 4; ++ks) {
        // x B-fragments straight from global: lane(l15,lg) reads
        // x[tt*16+l15][ks*32+lg*8 .. +8) as two float4s (coalesced, L1-hot)
        float4 xa[4], xc[4];
        #pragma unroll
        for (int tt = 0; tt < 4; ++tt) {
            const float* xp = xq + (tt * 16 + l15) * 128 + ks * 32 + lg * 8;
            xa[tt] = *(const float4*)(xp);
            xc[tt] = *(const float4*)(xp + 4);
        }
        bf16x8 xf[4];
        #pragma unroll
        for (int tt = 0; tt < 4; ++tt) xf[tt] = pack8(xa[tt], xc[tt]);

        #pragma unroll
        for (int j = 0; j < 3; ++j) {
            if (tile0 + j < 8) {
                #pragma unroll
                for (int tt = 0; tt < 4; ++tt)
                    acc[j][tt] = __builtin_amdgcn_mfma_f32_16x16x32_bf16(
                        wfr[j][ks], xf[tt], acc[j][tt], 0, 0, 0);
            } else {
                #pragma unroll
                for (int tt = 0; tt < 4; ++tt)
                    acc[j][tt] = __builtin_amdgcn_mfma_f32_16x16x32_bf16(
                        xf[tt], wfr[j][ks], acc[j][tt], 0, 0, 0);
            }
        }
    }

    // ---- write q/k ([t][h], b64) and v (VT [h][t], b64) -------------------
    #pragma unroll
    for (int j = 0; j < 3; ++j) {
        int tile = tile0 + j;
        if (tile < 8) {
            int base = (tile < 4) ? Q_OFF : K_OFF;
            int h0 = (tile & 3) * 16 + lg * 4;
            #pragma unroll
            for (int tt = 0; tt < 4; ++tt) {
                int tr = tt * 16 + l15;
                bf16x4 pk;
                pk[0] = (bf16_t)acc[j][tt][0]; pk[1] = (bf16_t)acc[j][tt][1];
                pk[2] = (bf16_t)acc[j][tt][2]; pk[3] = (bf16_t)acc[j][tt][3];
                *(bf16x4*)(smem + base + swz(tr * 128 + h0 * 2, tr)) = pk;
            }
        } else {
            int hv = (tile - 8) * 16 + l15;
            #pragma unroll
            for (int tt = 0; tt < 4; ++tt) {
                int t0 = tt * 16 + lg * 4;
                bf16x4 pk;
                pk[0] = (bf16_t)acc[j][tt][0]; pk[1] = (bf16_t)acc[j][tt][1];
                pk[2] = (bf16_t)acc[j][tt][2]; pk[3] = (bf16_t)acc[j][tt][3];
                *(bf16x4*)(smem + VT_OFF + swz(hv * 128 + t0 * 2, hv)) = pk;
            }
        }
    }
    lds_barrier();     // q/k/v visible block-wide

    // ------------- S^T = K . q^T : lane = col t (own row), regs = s --------
    f32x4 sacc[4];
    #pragma unroll
    for (int st = 0; st < 4; ++st) sacc[st] = (f32x4){0.f, 0.f, 0.f, 0.f};
    #pragma unroll
    for (int ks = 0; ks < 2; ++ks) {
        int h0 = ks * 32 + lg * 8;
        bf16x8 qf = *(const bf16x8*)(smem + Q_OFF + swz(t * 128 + h0 * 2, t));
        #pragma unroll
        for (int st = 0; st < 4; ++st) {
            int s = st * 16 + l15;
            bf16x8 kf = *(const bf16x8*)(smem + K_OFF + swz(s * 128 + h0 * 2, s));
            sacc[st] = __builtin_amdgcn_mfma_f32_16x16x32_bf16(kf, qf, sacc[st], 0, 0, 0);
        }
    }

    // ------------- softmax: each lane owns full row t ----------------------
    float p[4][4];
    float m = -1e30f;
    #pragma unroll
    for (int st = 0; st < 4; ++st)
        #pragma unroll
        for (int r = 0; r < 4; ++r) {
            int s = st * 16 + lg * 4 + r;
            float v = sacc[st][r] * 0.125f;
            v = (s <= t) ? v : -1e30f;     // causal
            p[st][r] = v;
            m = fmaxf(m, v);
        }
    m = fmaxf(m, __shfl_xor(m, 16));
    m = fmaxf(m, __shfl_xor(m, 32));
    float sum = 0.f;
    #pragma unroll
    for (int st = 0; st < 4; ++st)
        #pragma unroll
        for (int r = 0; r < 4; ++r) {
            float e = __expf(p[st][r] - m);
            p[st][r] = e;
            sum += e;
        }
    sum += __shfl_xor(sum, 16);
    sum += __shfl_xor(sum, 32);
    float inv = 1.0f / sum;
    // P overwrites Q chunk w: this wave's qf reads (above) are the only reads
    // of this chunk, already complete in program order -> wave-private, safe.
    #pragma unroll
    for (int st = 0; st < 4; ++st) {
        bf16x4 pk;
        pk[0] = (bf16_t)(p[st][0] * inv); pk[1] = (bf16_t)(p[st][1] * inv);
        pk[2] = (bf16_t)(p[st][2] * inv); pk[3] = (bf16_t)(p[st][3] * inv);
        *(bf16x4*)(pscr + swz(l15 * 128 + (st * 16 + lg * 4) * 2, l15)) = pk;
    }
    // same-wave LDS write->read, in-order, no barrier

    // ------------- out^T = V^T . P^T (swapped): lane = col t ---------------
    f32x4 oacc[4];
    #pragma unroll
    for (int ht = 0; ht < 4; ++ht) oacc[ht] = (f32x4){0.f, 0.f, 0.f, 0.f};
    #pragma unroll
    for (int ks = 0; ks < 2; ++ks) {
        int s0 = ks * 32 + lg * 8;
        bf16x8 pf = *(const bf16x8*)(pscr + swz(l15 * 128 + s0 * 2, l15));
        #pragma unroll
        for (int ht = 0; ht < 4; ++ht) {
            int h = ht * 16 + l15;
            bf16x8 vf = *(const bf16x8*)(smem + VT_OFF + swz(h * 128 + s0 * 2, h));
            oacc[ht] = __builtin_amdgcn_mfma_f32_16x16x32_bf16(vf, pf, oacc[ht], 0, 0, 0);
        }
    }

    float* ob = out + (size_t)b * 4096 + t * 64 + lg * 4;
    #pragma unroll
    for (int ht = 0; ht < 4; ++ht)
        *(float4*)(ob + ht * 16) =
            (float4){oacc[ht][0], oacc[ht][1], oacc[ht][2], oacc[ht][3]};
}

extern "C" void kernel_launch(void* const* d_in, const int* in_sizes, int n_in,
                              void* d_out, int out_size, void* d_ws, size_t ws_size,
                              hipStream_t stream) {
    const float* x  = (const float*)d_in[0];
    const float* Wq = (const float*)d_in[1];
    const float* Wk = (const float*)d_in[2];
    const float* Wv = (const float*)d_in[3];
    float* out = (float*)d_out;
    int B = in_sizes[0] / (64 * 128);   // 4096
    head_attn_kernel<<<B, 256, 0, stream>>>(x, Wq, Wk, Wv, out);
}

// Round 17
// 111.185 us; speedup vs baseline: 1.0682x; 1.0682x over previous
//
#include <hip/hip_runtime.h>
#include <hip/hip_bf16.h>

// Single-head causal attention, B=4096, T=64, C=128, H=64.
// R17 = R14 (PASSED: 1 batch/block, single-pass QKV, x direct from global,
// 24KB LDS, one barrier) with ONE structural delta: W fragments are NOT
// persistent -- re-loaded per-ks from global (W is 96KB, L2-resident).
// Frees 48 regs -> demand ~124 <= 128 -> 4 waves/EU packable. LDS 24KB
// allows 4 blocks/CU -> target 16 waves/CU (2x the 44us plateau's TLP).
// waves_per_eu(2,4): min 2 avoids forced-spill (R12/R14 lesson), max 4
// lets HW pack 4/EU when the natural allocation fits.

typedef __bf16 bf16_t;
typedef __bf16 bf16x8 __attribute__((ext_vector_type(8)));
typedef __bf16 bf16x4 __attribute__((ext_vector_type(4)));
typedef float  f32x4  __attribute__((ext_vector_type(4)));

#define Q_OFF   0        // Q [t][h] 64x64 bf16, swizzled, 8 KB; chunk w reused as P
#define K_OFF   8192     // K [s][h] 8 KB
#define VT_OFF  16384    // VT [h][t] 8 KB
#define LDS_BYTES 24576  // 24 KB

__device__ __forceinline__ int swz(int off, int row) { return off ^ ((row & 7) << 4); }

__device__ __forceinline__ bf16x8 pack8(float4 a, float4 b) {
    bf16x8 r;
    r[0] = (bf16_t)a.x; r[1] = (bf16_t)a.y; r[2] = (bf16_t)a.z; r[3] = (bf16_t)a.w;
    r[4] = (bf16_t)b.x; r[5] = (bf16_t)b.y; r[6] = (bf16_t)b.z; r[7] = (bf16_t)b.w;
    return r;
}

__global__ __launch_bounds__(256) __attribute__((amdgpu_waves_per_eu(2, 4)))
void head_attn_kernel(const float* __restrict__ x,
                      const float* __restrict__ Wq,
                      const float* __restrict__ Wk,
                      const float* __restrict__ Wv,
                      float* __restrict__ out)
{
    __shared__ __align__(16) char smem[LDS_BYTES];
    const int b    = blockIdx.x;
    const int tid  = threadIdx.x;
    const int w    = tid >> 6;
    const int lane = tid & 63;
    const int l15  = lane & 15;
    const int lg   = lane >> 4;
    const int t    = w * 16 + l15;      // lane's query/time row (attention)
    const int tile0 = 3 * w;            // this wave's first h-tile
    char* pscr = smem + Q_OFF + w * 2048;   // P scratch = Q chunk w (wave-private)

    const float* xq = x + (size_t)b * 8192;

    // ---- hoisted per-lane W row pointers for this wave's 3 h-tiles --------
    const float* wrp[3];
    #pragma unroll
    for (int j = 0; j < 3; ++j) {
        int hg = (tile0 + j) * 16 + l15;
        wrp[j] = (hg < 64)  ? Wq + hg * 128
               : (hg < 128) ? Wk + (hg - 64) * 128
                            : Wv + (hg - 128) * 128;
    }

    // ------------- QKV: wave's 3 h-tiles x all 4 t-tiles -------------------
    // tile<8 (q/k): mfma(wf, xf) -> lane = t, regs = h   [R8-validated]
    // tile>=8 (v):  mfma(xf, wf) -> lane = h, regs = t   [R8-validated]
    f32x4 acc[3][4];
    #pragma unroll
    for (int j = 0; j < 3; ++j)
        #pragma unroll
        for (int tt = 0; tt < 4; ++tt) acc[j][tt] = (f32x4){0.f, 0.f, 0.f, 0.f};

    #pragma unroll
    for (int ks = 0; ks < 4; ++ks) {
        // W fragments for THIS ks only (transient, 12 regs; W is L2-resident)
        float4 wa[3], wc[3];
        #pragma unroll
        for (int j = 0; j < 3; ++j) {
            wa[j] = *(const float4*)(wrp[j] + ks * 32 + lg * 8);
            wc[j] = *(const float4*)(wrp[j] + ks * 32 + lg * 8 + 4);
        }
        // x B-fragments straight from global (coalesced, L1/L2-hot)
        float4 xa[4], xc[4];
        #pragma unroll
        for (int tt = 0; tt < 4; ++tt) {
            const float* xp = xq + (tt * 16 + l15) * 128 + ks * 32 + lg * 8;
            xa[tt] = *(const float4*)(xp);
            xc[tt] = *(const float4*)(xp + 4);
        }
        bf16x8 wf[3];
        #pragma unroll
        for (int j = 0; j < 3; ++j) wf[j] = pack8(wa[j], wc[j]);
        bf16x8 xf[4];
        #pragma unroll
        for (int tt = 0; tt < 4; ++tt) xf[tt] = pack8(xa[tt], xc[tt]);

        #pragma unroll
        for (int j = 0; j < 3; ++j) {
            if (tile0 + j < 8) {
                #pragma unroll
                for (int tt = 0; tt < 4; ++tt)
                    acc[j][tt] = __builtin_amdgcn_mfma_f32_16x16x32_bf16(
                        wf[j], xf[tt], acc[j][tt], 0, 0, 0);
            } else {
                #pragma unroll
                for (int tt = 0; tt < 4; ++tt)
                    acc[j][tt] = __builtin_amdgcn_mfma_f32_16x16x32_bf16(
                        xf[tt], wf[j], acc[j][tt], 0, 0, 0);
            }
        }
    }

    // ---- write q/k ([t][h], b64) and v (VT [h][t], b64) -------------------
    #pragma unroll
    for (int j = 0; j < 3; ++j) {
        int tile = tile0 + j;
        if (tile < 8) {
            int base = (tile < 4) ? Q_OFF : K_OFF;
            int h0 = (tile & 3) * 16 + lg * 4;
            #pragma unroll
            for (int tt = 0; tt < 4; ++tt) {
                int tr = tt * 16 + l15;
                bf16x4 pk;
                pk[0] = (bf16_t)acc[j][tt][0]; pk[1] = (bf16_t)acc[j][tt][1];
                pk[2] = (bf16_t)acc[j][tt][2]; pk[3] = (bf16_t)acc[j][tt][3];
                *(bf16x4*)(smem + base + swz(tr * 128 + h0 * 2, tr)) = pk;
            }
        } else {
            int hv = (tile - 8) * 16 + l15;
            #pragma unroll
            for (int tt = 0; tt < 4; ++tt) {
                int t0 = tt * 16 + lg * 4;
                bf16x4 pk;
                pk[0] = (bf16_t)acc[j][tt][0]; pk[1] = (bf16_t)acc[j][tt][1];
                pk[2] = (bf16_t)acc[j][tt][2]; pk[3] = (bf16_t)acc[j][tt][3];
                *(bf16x4*)(smem + VT_OFF + swz(hv * 128 + t0 * 2, hv)) = pk;
            }
        }
    }
    __syncthreads();     // q/k/v visible block-wide

    // ------------- S^T = K . q^T : lane = col t (own row), regs = s --------
    f32x4 sacc[4];
    #pragma unroll
    for (int st = 0; st < 4; ++st) sacc[st] = (f32x4){0.f, 0.f, 0.f, 0.f};
    #pragma unroll
    for (int ks = 0; ks < 2; ++ks) {
        int h0 = ks * 32 + lg * 8;
        bf16x8 qf = *(const bf16x8*)(smem + Q_OFF + swz(t * 128 + h0 * 2, t));
        #pragma unroll
        for (int st = 0; st < 4; ++st) {
            int s = st * 16 + l15;
            bf16x8 kf = *(const bf16x8*)(smem + K_OFF + swz(s * 128 + h0 * 2, s));
            sacc[st] = __builtin_amdgcn_mfma_f32_16x16x32_bf16(kf, qf, sacc[st], 0, 0, 0);
        }
    }

    // ------------- softmax: each lane owns full row t ----------------------
    float p[4][4];
    float m = -1e30f;
    #pragma unroll
    for (int st = 0; st < 4; ++st)
        #pragma unroll
        for (int r = 0; r < 4; ++r) {
            int s = st * 16 + lg * 4 + r;
            float v = sacc[st][r] * 0.125f;
            v = (s <= t) ? v : -1e30f;     // causal
            p[st][r] = v;
            m = fmaxf(m, v);
        }
    m = fmaxf(m, __shfl_xor(m, 16));
    m = fmaxf(m, __shfl_xor(m, 32));
    float sum = 0.f;
    #pragma unroll
    for (int st = 0; st < 4; ++st)
        #pragma unroll
        for (int r = 0; r < 4; ++r) {
            float e = __expf(p[st][r] - m);
            p[st][r] = e;
            sum += e;
        }
    sum += __shfl_xor(sum, 16);
    sum += __shfl_xor(sum, 32);
    float inv = 1.0f / sum;
    // P overwrites Q chunk w: after the barrier, chunk w is read ONLY by wave
    // w (qf above), whose reads precede these writes in program order (R14).
    #pragma unroll
    for (int st = 0; st < 4; ++st) {
        bf16x4 pk;
        pk[0] = (bf16_t)(p[st][0] * inv); pk[1] = (bf16_t)(p[st][1] * inv);
        pk[2] = (bf16_t)(p[st][2] * inv); pk[3] = (bf16_t)(p[st][3] * inv);
        *(bf16x4*)(pscr + swz(l15 * 128 + (st * 16 + lg * 4) * 2, l15)) = pk;
    }
    // same-wave LDS write->read, in-order, no barrier

    // ------------- out^T = V^T . P^T (swapped): lane = col t ---------------
    f32x4 oacc[4];
    #pragma unroll
    for (int ht = 0; ht < 4; ++ht) oacc[ht] = (f32x4){0.f, 0.f, 0.f, 0.f};
    #pragma unroll
    for (int ks = 0; ks < 2; ++ks) {
        int s0 = ks * 32 + lg * 8;
        bf16x8 pf = *(const bf16x8*)(pscr + swz(l15 * 128 + s0 * 2, l15));
        #pragma unroll
        for (int ht = 0; ht < 4; ++ht) {
            int h = ht * 16 + l15;
            bf16x8 vf = *(const bf16x8*)(smem + VT_OFF + swz(h * 128 + s0 * 2, h));
            oacc[ht] = __builtin_amdgcn_mfma_f32_16x16x32_bf16(vf, pf, oacc[ht], 0, 0, 0);
        }
    }

    float* ob = out + (size_t)b * 4096 + t * 64 + lg * 4;
    #pragma unroll
    for (int ht = 0; ht < 4; ++ht)
        *(float4*)(ob + ht * 16) =
            (float4){oacc[ht][0], oacc[ht][1], oacc[ht][2], oacc[ht][3]};
}

extern "C" void kernel_launch(void* const* d_in, const int* in_sizes, int n_in,
                              void* d_out, int out_size, void* d_ws, size_t ws_size,
                              hipStream_t stream) {
    const float* x  = (const float*)d_in[0];
    const float* Wq = (const float*)d_in[1];
    const float* Wk = (const float*)d_in[2];
    const float* Wv = (const float*)d_in[3];
    float* out = (float*)d_out;
    int B = in_sizes[0] / (64 * 128);   // 4096
    head_attn_kernel<<<B, 256, 0, stream>>>(x, Wq, Wk, Wv, out);
}